// Round 9
// baseline (109.033 us; speedup 1.0000x reference)
//
#include <hip/hip_runtime.h>
#include <math.h>

#define SIG_THRESHOLD 0.01f
#define PHASE_INT_THR 0.01f

typedef float f32x2 __attribute__((ext_vector_type(2)));
typedef float f32x4 __attribute__((ext_vector_type(4)));

// ---------------- inline-asm load machinery ----------------
// Compiler never keeps >1 load in flight here (R2-R8: VGPR pinned to 32,
// ~4 serialized latencies/iter). Force it: asm loads into pinned regs,
// counted vmcnt, sched_barrier fences (skill rule #18).
__device__ __forceinline__ void gl4(const f32x4* p, f32x4& d) {
    asm volatile("global_load_dwordx4 %0, %1, off" : "=v"(d) : "v"(p));
}
template<int N>
__device__ __forceinline__ void wait_vm() {
    asm volatile("s_waitcnt vmcnt(%0)" :: "i"(N) : "memory");
    __builtin_amdgcn_sched_barrier(0);
}

// ---------------- packed-pair fast atan2 + phase-diff^2 ----------------
// Verified absmax 0.0 (R5-R8).
__device__ __forceinline__ f32x2 phase_term_pair(f32x2 lr, f32x2 li, f32x2 pr, f32x2 pi,
                                                 f32x2 lint) {
    f32x2 cross = pi * lr - pr * li;
    f32x2 dotv  = pr * lr + pi * li;

    f32x2 ax = __builtin_elementwise_abs(dotv);
    f32x2 ay = __builtin_elementwise_abs(cross);
    f32x2 mx = __builtin_elementwise_max(ax, ay);
    f32x2 mn = __builtin_elementwise_min(ax, ay);
    f32x2 rcp;
    rcp.x = __builtin_amdgcn_rcpf(mx.x);
    rcp.y = __builtin_amdgcn_rcpf(mx.y);
    f32x2 t = mn * rcp;
    t.x = (mx.x == 0.0f) ? 0.0f : t.x;     // atan2(0,0) -> 0
    t.y = (mx.y == 0.0f) ? 0.0f : t.y;

    f32x2 s = t * t;
    f32x2 p = s * (-0.01172120f) + 0.05265332f;
    p = s * p + (-0.11643287f);
    p = s * p + 0.19354346f;
    p = s * p + (-0.33262347f);
    p = s * p + 0.99997726f;
    f32x2 r = p * t;                        // atan(mn/mx) in [0, pi/4]

    f32x2 rq  = 1.57079632679f - r;
    r.x = (ay.x > ax.x) ? rq.x : r.x;
    r.y = (ay.y > ax.y) ? rq.y : r.y;
    f32x2 rpi = 3.14159265359f - r;
    r.x = (dotv.x < 0.0f) ? rpi.x : r.x;
    r.y = (dotv.y < 0.0f) ? rpi.y : r.y;
    r.x = copysignf(r.x, cross.x);          // w
    r.y = copysignf(r.y, cross.y);

    float sg0, sg1;
    {
        bool php = pi.x > 0.0f, phl = li.x > 0.0f;
        sg0 = (php && !phl && r.x < 0.0f) ? 1.0f
            : ((!php && phl && r.x > 0.0f) ? -1.0f : 0.0f);
        php = pi.y > 0.0f; phl = li.y > 0.0f;
        sg1 = (php && !phl && r.y < 0.0f) ? 1.0f
            : ((!php && phl && r.y > 0.0f) ? -1.0f : 0.0f);
    }
    f32x2 sg; sg.x = sg0; sg.y = sg1;
    f32x2 dph2 = sg * (12.566370614f * r + 39.4784176044f * sg) + r * r;

    dph2.x = (lint.x >= PHASE_INT_THR) ? dph2.x : 0.0f;
    dph2.y = (lint.y >= PHASE_INT_THR) ? dph2.y : 0.0f;
    return dph2;
}

__device__ __forceinline__ void process_pair(f32x2 lr, f32x2 li, f32x2 pr, f32x2 pi,
                                             f32x2& sr, f32x2& si, f32x2& sint, f32x2& sph) {
    f32x2 dr = pr - lr;  sr += dr * dr;
    f32x2 di = pi - li;  si += di * di;
    f32x2 lint = lr * lr + li * li;
    f32x2 pint = pr * pr + pi * pi;
    f32x2 dint = pint - lint;  sint += dint * dint;
    sph += phase_term_pair(lr, li, pr, pi, lint);
}

#define COARSE_SENT (1 << 29)

__device__ __forceinline__ void process_quad(f32x4 a, f32x4 b, f32x4 c, f32x4 d, int v,
                                             f32x2& sr, f32x2& si, f32x2& sint, f32x2& sph,
                                             int4& bounds) {
    f32x2 lr0; lr0.x = a.x; lr0.y = a.y;
    f32x2 lr1; lr1.x = a.z; lr1.y = a.w;
    f32x2 li0; li0.x = b.x; li0.y = b.y;
    f32x2 li1; li1.x = b.z; li1.y = b.w;
    f32x2 pr0; pr0.x = c.x; pr0.y = c.y;
    f32x2 pr1; pr1.x = c.z; pr1.y = c.w;
    f32x2 pi0; pi0.x = d.x; pi0.y = d.y;
    f32x2 pi1; pi1.x = d.z; pi1.y = d.w;

    process_pair(lr0, li0, pr0, pi0, sr, si, sint, sph);
    process_pair(lr1, li1, pr1, pi1, sr, si, sint, sph);

    float amr = fmaxf(fmaxf(fmaxf(fabsf(a.x), fabsf(a.y)), fabsf(a.z)), fabsf(a.w));
    float ami = fmaxf(fmaxf(fmaxf(fabsf(b.x), fabsf(b.y)), fabsf(b.z)), fabsf(b.w));
    bool srb = amr > SIG_THRESHOLD;
    bool sib = ami > SIG_THRESHOLD;
    bounds.x = min(bounds.x, srb ? v : COARSE_SENT);
    bounds.y = srb ? v : bounds.y;          // v monotone increasing per thread
    bounds.z = min(bounds.z, sib ? v : COARSE_SENT);
    bounds.w = sib ? v : bounds.w;
}

// ---------------- fused block reductions ----------------

__device__ __forceinline__ float4 waveReduceSum4(float4 v) {
#pragma unroll
    for (int o = 32; o > 0; o >>= 1) {
        v.x += __shfl_down(v.x, o, 64);
        v.y += __shfl_down(v.y, o, 64);
        v.z += __shfl_down(v.z, o, 64);
        v.w += __shfl_down(v.w, o, 64);
    }
    return v;
}

__device__ __forceinline__ int4 waveReduceBounds(int4 v) {
#pragma unroll
    for (int o = 32; o > 0; o >>= 1) {
        v.x = min(v.x, __shfl_down(v.x, o, 64));
        v.y = max(v.y, __shfl_down(v.y, o, 64));
        v.z = min(v.z, __shfl_down(v.z, o, 64));
        v.w = max(v.w, __shfl_down(v.w, o, 64));
    }
    return v;
}

__device__ __forceinline__ float4 blockReduceSum4(float4 v, float4* lds4) {
    __syncthreads();
    v = waveReduceSum4(v);
    int lane = threadIdx.x & 63, wave = threadIdx.x >> 6;
    if (lane == 0) lds4[wave] = v;
    __syncthreads();
    int nw = blockDim.x >> 6;
    float4 r = (threadIdx.x < nw) ? lds4[threadIdx.x] : make_float4(0.f, 0.f, 0.f, 0.f);
    if (threadIdx.x < 64) r = waveReduceSum4(r);
    if (threadIdx.x == 0) lds4[0] = r;
    __syncthreads();
    return lds4[0];
}

__device__ __forceinline__ int4 blockReduceBounds(int4 v, int4* ldsi4) {
    __syncthreads();
    v = waveReduceBounds(v);
    int lane = threadIdx.x & 63, wave = threadIdx.x >> 6;
    if (lane == 0) ldsi4[wave] = v;
    __syncthreads();
    int nw = blockDim.x >> 6;
    int4 r = (threadIdx.x < nw) ? ldsi4[threadIdx.x]
                                : make_int4(COARSE_SENT, -1, COARSE_SENT, -1);
    if (threadIdx.x < 64) r = waveReduceBounds(r);
    if (threadIdx.x == 0) ldsi4[0] = r;
    __syncthreads();
    return ldsi4[0];
}

// issue one 8-load group (2 float4 indices x 4 streams) into buffer X
#define IG(X, vb) \
    gl4(Lr4v + (vb), X##0); gl4(Li4v + (vb), X##1); \
    gl4(Pr4v + (vb), X##2); gl4(Pi4v + (vb), X##3); \
    gl4(Lr4v + (vb) + nt, X##4); gl4(Li4v + (vb) + nt, X##5); \
    gl4(Pr4v + (vb) + nt, X##6); gl4(Pi4v + (vb) + nt, X##7);

// compute one group from buffer X
#define CG(X, vb) \
    process_quad(X##0, X##1, X##2, X##3, (vb), sr, si, sint, sph, bounds); \
    process_quad(X##4, X##5, X##6, X##7, (vb) + nt, sr, si, sint, sph, bounds);

// ---------------- main per-row kernel ----------------
__global__ void __launch_bounds__(512) __attribute__((amdgpu_waves_per_eu(2, 4)))
prl_row_kernel(const float* __restrict__ pred, const float* __restrict__ label,
               float* __restrict__ row_out, int n, int two_n) {
    __shared__ float4 s_f4[8];
    __shared__ int4 s_i4[8];
    __shared__ int s_b[4];

    const int row = blockIdx.x;
    const float* __restrict__ P = pred  + (size_t)row * two_n;
    const float* __restrict__ L = label + (size_t)row * two_n;
    const int tid = threadIdx.x;
    const int nt  = blockDim.x;

    f32x2 sr = {0.f, 0.f}, si = {0.f, 0.f}, sint = {0.f, 0.f}, sph = {0.f, 0.f};
    int4 bounds = make_int4(COARSE_SENT, -1, COARSE_SENT, -1);

    const int nvec = n / 4;                  // 8192 float4s per half-row

    if (nvec == 16 * nt) {
        // ---- asm-pipelined fast path: A/B double-buffer of 8-load groups,
        // counted vmcnt(8) (never 0 mid-stream), 8 KB in flight per wave ----
        const f32x4* Lr4v = reinterpret_cast<const f32x4*>(L);
        const f32x4* Li4v = reinterpret_cast<const f32x4*>(L + n);
        const f32x4* Pr4v = reinterpret_cast<const f32x4*>(P);
        const f32x4* Pi4v = reinterpret_cast<const f32x4*>(P + n);

        f32x4 A0, A1, A2, A3, A4, A5, A6, A7;
        f32x4 B0, B1, B2, B3, B4, B5, B6, B7;

        // prologue: groups 0 (A) and 1 (B) -> 16 loads outstanding
        IG(A, tid);
        IG(B, tid + 2 * nt);

        // round 0
        wait_vm<8>();  CG(A, tid);              IG(A, tid + 4 * nt);
        wait_vm<8>();  CG(B, tid + 2 * nt);     IG(B, tid + 6 * nt);
        // round 1
        wait_vm<8>();  CG(A, tid + 4 * nt);     IG(A, tid + 8 * nt);
        wait_vm<8>();  CG(B, tid + 6 * nt);     IG(B, tid + 10 * nt);
        // round 2
        wait_vm<8>();  CG(A, tid + 8 * nt);     IG(A, tid + 12 * nt);
        wait_vm<8>();  CG(B, tid + 10 * nt);    IG(B, tid + 14 * nt);
        // round 3 (drain)
        wait_vm<8>();  CG(A, tid + 12 * nt);
        wait_vm<0>();  CG(B, tid + 14 * nt);
    } else {
        // generic fallback
        const f32x4* Lr4v = reinterpret_cast<const f32x4*>(L);
        const f32x4* Li4v = reinterpret_cast<const f32x4*>(L + n);
        const f32x4* Pr4v = reinterpret_cast<const f32x4*>(P);
        const f32x4* Pi4v = reinterpret_cast<const f32x4*>(P + n);
        for (int v = tid; v < nvec; v += nt) {
            f32x4 a = Lr4v[v], b = Li4v[v], c = Pr4v[v], d = Pi4v[v];
            process_quad(a, b, c, d, v, sr, si, sint, sph, bounds);
        }
    }

    float4 sums = make_float4(sr.x + sr.y, si.x + si.y, sint.x + sint.y, sph.x + sph.y);
    float4 tot = blockReduceSum4(sums, s_f4);
    int4 b4 = blockReduceBounds(bounds, s_i4);

    // refine coarse (float4-granularity) bounds to exact element bounds
    if (tid < 4) s_b[tid] = (tid & 1) ? -1 : n;
    __syncthreads();
    if (tid < 16) {
        int which = tid >> 2;                     // 0:fr 1:lr 2:fi 3:li
        int k = tid & 3;
        const float* base = (which >= 2) ? (L + n) : L;
        int v4 = (which == 0) ? b4.x : (which == 1) ? b4.y : (which == 2) ? b4.z : b4.w;
        bool valid = (which & 1) ? (v4 >= 0) : (v4 < COARSE_SENT);
        if (valid) {
            int idx = v4 * 4 + k;
            if (fabsf(base[idx]) > SIG_THRESHOLD) {
                if (which & 1) atomicMax(&s_b[which], idx);
                else           atomicMin(&s_b[which], idx);
            }
        }
    }
    __syncthreads();
    int fr = s_b[0], lr = s_b[1], fi = s_b[2], li = s_b[3];
    if (fr == n) { fr = 0; lr = n - 1; }   // no significant element: scale 1 everywhere
    if (fi == n) { fi = 0; li = n - 1; }

    // extra 1x contribution for the two outside spans (usually ~empty)
    float4 osum = make_float4(0.f, 0.f, 0.f, 0.f);   // x: o_r, y: o_i
    for (int i = tid; i < fr; i += nt)          { float d = P[i] - L[i];         osum.x = fmaf(d, d, osum.x); }
    for (int i = lr + 1 + tid; i < n; i += nt)  { float d = P[i] - L[i];         osum.x = fmaf(d, d, osum.x); }
    for (int i = tid; i < fi; i += nt)          { float d = P[n + i] - L[n + i]; osum.y = fmaf(d, d, osum.y); }
    for (int i = li + 1 + tid; i < n; i += nt)  { float d = P[n + i] - L[n + i]; osum.y = fmaf(d, d, osum.y); }

    float4 otot = blockReduceSum4(osum, s_f4);

    if (tid == 0) {
        float wr = tot.x + otot.x;
        float wi = tot.y + otot.y;
        row_out[row] = (wr + wi + 10.0f * tot.z + 5.0f * tot.w) / (float)n;
    }
}

// ---------------- finalize: mean over rows ----------------
__global__ void __launch_bounds__(1024)
prl_finalize_kernel(const float* __restrict__ rows, float* __restrict__ out, int B) {
    __shared__ float4 s_f4[16];
    float4 v = make_float4(0.f, 0.f, 0.f, 0.f);
    for (int i = threadIdx.x; i < B; i += blockDim.x) v.x += rows[i];
    __syncthreads();
    v = waveReduceSum4(v);
    int lane = threadIdx.x & 63, wave = threadIdx.x >> 6;
    if (lane == 0) s_f4[wave] = v;
    __syncthreads();
    int nw = blockDim.x >> 6;
    float4 r = (threadIdx.x < nw) ? s_f4[threadIdx.x] : make_float4(0.f, 0.f, 0.f, 0.f);
    if (threadIdx.x < 64) r = waveReduceSum4(r);
    if (threadIdx.x == 0) out[0] = r.x / (float)B;
}

extern "C" void kernel_launch(void* const* d_in, const int* in_sizes, int n_in,
                              void* d_out, int out_size, void* d_ws, size_t ws_size,
                              hipStream_t stream) {
    const float* pred  = (const float*)d_in[0];
    const float* label = (const float*)d_in[1];
    // spectrogram (d_in[2]) is unused by the reference.

    const int B     = in_sizes[2] / (128 * 128);   // 1024
    const int two_n = in_sizes[0] / B;             // 65536
    const int n     = two_n / 2;                   // 32768

    float* row_out = (float*)d_ws;                 // B floats of scratch
    float* out     = (float*)d_out;

    prl_row_kernel<<<B, 512, 0, stream>>>(pred, label, row_out, n, two_n);
    prl_finalize_kernel<<<1, 1024, 0, stream>>>(row_out, out, B);
}

// Round 10
// 107.440 us; speedup vs baseline: 1.0148x; 1.0148x over previous
//
#include <hip/hip_runtime.h>
#include <math.h>

#define SIG_THRESHOLD 0.01f
#define PHASE_INT_THR 0.01f

typedef float f32x2 __attribute__((ext_vector_type(2)));
typedef float f32x4 __attribute__((ext_vector_type(4)));

// ---------------- packed-pair fast atan2 + phase-diff^2 ----------------
// Verified absmax 0.0 (R5-R9).
__device__ __forceinline__ f32x2 phase_term_pair(f32x2 lr, f32x2 li, f32x2 pr, f32x2 pi,
                                                 f32x2 lint) {
    f32x2 cross = pi * lr - pr * li;
    f32x2 dotv  = pr * lr + pi * li;

    f32x2 ax = __builtin_elementwise_abs(dotv);
    f32x2 ay = __builtin_elementwise_abs(cross);
    f32x2 mx = __builtin_elementwise_max(ax, ay);
    f32x2 mn = __builtin_elementwise_min(ax, ay);
    f32x2 rcp;
    rcp.x = __builtin_amdgcn_rcpf(mx.x);
    rcp.y = __builtin_amdgcn_rcpf(mx.y);
    f32x2 t = mn * rcp;
    t.x = (mx.x == 0.0f) ? 0.0f : t.x;     // atan2(0,0) -> 0
    t.y = (mx.y == 0.0f) ? 0.0f : t.y;

    f32x2 s = t * t;
    f32x2 p = s * (-0.01172120f) + 0.05265332f;
    p = s * p + (-0.11643287f);
    p = s * p + 0.19354346f;
    p = s * p + (-0.33262347f);
    p = s * p + 0.99997726f;
    f32x2 r = p * t;                        // atan(mn/mx) in [0, pi/4]

    f32x2 rq  = 1.57079632679f - r;
    r.x = (ay.x > ax.x) ? rq.x : r.x;
    r.y = (ay.y > ax.y) ? rq.y : r.y;
    f32x2 rpi = 3.14159265359f - r;
    r.x = (dotv.x < 0.0f) ? rpi.x : r.x;
    r.y = (dotv.y < 0.0f) ? rpi.y : r.y;
    r.x = copysignf(r.x, cross.x);          // w
    r.y = copysignf(r.y, cross.y);

    // unwrap sign: +1 iff (pi>0 & li<=0 & w<0); -1 iff (pi<=0 & li>0 & w>0)
    float sg0, sg1;
    {
        bool php = pi.x > 0.0f, phl = li.x > 0.0f;
        sg0 = (php && !phl && r.x < 0.0f) ? 1.0f
            : ((!php && phl && r.x > 0.0f) ? -1.0f : 0.0f);
        php = pi.y > 0.0f; phl = li.y > 0.0f;
        sg1 = (php && !phl && r.y < 0.0f) ? 1.0f
            : ((!php && phl && r.y > 0.0f) ? -1.0f : 0.0f);
    }
    // dph^2 = w^2 + sg*(4pi*w + 4pi^2*sg)
    f32x2 sg; sg.x = sg0; sg.y = sg1;
    f32x2 dph2 = sg * (12.566370614f * r + 39.4784176044f * sg) + r * r;

    dph2.x = (lint.x >= PHASE_INT_THR) ? dph2.x : 0.0f;
    dph2.y = (lint.y >= PHASE_INT_THR) ? dph2.y : 0.0f;
    return dph2;
}

__device__ __forceinline__ void process_pair(f32x2 lr, f32x2 li, f32x2 pr, f32x2 pi,
                                             f32x2& sr, f32x2& si, f32x2& sint, f32x2& sph) {
    f32x2 dr = pr - lr;  sr += dr * dr;
    f32x2 di = pi - li;  si += di * di;
    f32x2 lint = lr * lr + li * li;
    f32x2 pint = pr * pr + pi * pi;
    f32x2 dint = pint - lint;  sint += dint * dint;
    sph += phase_term_pair(lr, li, pr, pi, lint);
}

#define COARSE_SENT (1 << 29)

// NOTE: with staggered iteration order, v is NOT monotone per thread ->
// last-significant tracking uses max (one extra op vs R7).
__device__ __forceinline__ void process_quad(f32x4 a, f32x4 b, f32x4 c, f32x4 d, int v,
                                             f32x2& sr, f32x2& si, f32x2& sint, f32x2& sph,
                                             int4& bounds) {
    f32x2 lr0; lr0.x = a.x; lr0.y = a.y;
    f32x2 lr1; lr1.x = a.z; lr1.y = a.w;
    f32x2 li0; li0.x = b.x; li0.y = b.y;
    f32x2 li1; li1.x = b.z; li1.y = b.w;
    f32x2 pr0; pr0.x = c.x; pr0.y = c.y;
    f32x2 pr1; pr1.x = c.z; pr1.y = c.w;
    f32x2 pi0; pi0.x = d.x; pi0.y = d.y;
    f32x2 pi1; pi1.x = d.z; pi1.y = d.w;

    process_pair(lr0, li0, pr0, pi0, sr, si, sint, sph);
    process_pair(lr1, li1, pr1, pi1, sr, si, sint, sph);

    float amr = fmaxf(fmaxf(fmaxf(fabsf(a.x), fabsf(a.y)), fabsf(a.z)), fabsf(a.w));
    float ami = fmaxf(fmaxf(fmaxf(fabsf(b.x), fabsf(b.y)), fabsf(b.z)), fabsf(b.w));
    bool srb = amr > SIG_THRESHOLD;
    bool sib = ami > SIG_THRESHOLD;
    bounds.x = min(bounds.x, srb ? v : COARSE_SENT);
    bounds.y = max(bounds.y, srb ? v : -1);
    bounds.z = min(bounds.z, sib ? v : COARSE_SENT);
    bounds.w = max(bounds.w, sib ? v : -1);
}

// ---------------- fused block reductions ----------------

__device__ __forceinline__ float4 waveReduceSum4(float4 v) {
#pragma unroll
    for (int o = 32; o > 0; o >>= 1) {
        v.x += __shfl_down(v.x, o, 64);
        v.y += __shfl_down(v.y, o, 64);
        v.z += __shfl_down(v.z, o, 64);
        v.w += __shfl_down(v.w, o, 64);
    }
    return v;
}

__device__ __forceinline__ int4 waveReduceBounds(int4 v) {
#pragma unroll
    for (int o = 32; o > 0; o >>= 1) {
        v.x = min(v.x, __shfl_down(v.x, o, 64));
        v.y = max(v.y, __shfl_down(v.y, o, 64));
        v.z = min(v.z, __shfl_down(v.z, o, 64));
        v.w = max(v.w, __shfl_down(v.w, o, 64));
    }
    return v;
}

__device__ __forceinline__ float4 blockReduceSum4(float4 v, float4* lds4) {
    __syncthreads();
    v = waveReduceSum4(v);
    int lane = threadIdx.x & 63, wave = threadIdx.x >> 6;
    if (lane == 0) lds4[wave] = v;
    __syncthreads();
    int nw = blockDim.x >> 6;
    float4 r = (threadIdx.x < nw) ? lds4[threadIdx.x] : make_float4(0.f, 0.f, 0.f, 0.f);
    if (threadIdx.x < 64) r = waveReduceSum4(r);
    if (threadIdx.x == 0) lds4[0] = r;
    __syncthreads();
    return lds4[0];
}

__device__ __forceinline__ int4 blockReduceBounds(int4 v, int4* ldsi4) {
    __syncthreads();
    v = waveReduceBounds(v);
    int lane = threadIdx.x & 63, wave = threadIdx.x >> 6;
    if (lane == 0) ldsi4[wave] = v;
    __syncthreads();
    int nw = blockDim.x >> 6;
    int4 r = (threadIdx.x < nw) ? ldsi4[threadIdx.x]
                                : make_int4(COARSE_SENT, -1, COARSE_SENT, -1);
    if (threadIdx.x < 64) r = waveReduceBounds(r);
    if (threadIdx.x == 0) ldsi4[0] = r;
    __syncthreads();
    return ldsi4[0];
}

// ---------------- main per-row kernel ----------------
// Wave-staggered iteration order: wave w visits float4-slot (j + 2w) mod 16.
// Same coverage & coalescing; the 8 waves of a block sit at 8 different
// memory phases -> one wave's VALU overlaps another wave's loads (convoy
// breaking). R2-R9 showed per-wave in-flight depth is NOT the constraint;
// cross-wave phase diversity is the remaining lever.
__global__ void __launch_bounds__(512)
prl_row_kernel(const float* __restrict__ pred, const float* __restrict__ label,
               float* __restrict__ row_out, int n, int two_n) {
    __shared__ float4 s_f4[8];
    __shared__ int4 s_i4[8];
    __shared__ int s_b[4];

    const int row = blockIdx.x;
    const float* __restrict__ P = pred  + (size_t)row * two_n;
    const float* __restrict__ L = label + (size_t)row * two_n;
    const int tid = threadIdx.x;
    const int nt  = blockDim.x;

    const f32x4* __restrict__ Lr4 = reinterpret_cast<const f32x4*>(L);
    const f32x4* __restrict__ Li4 = reinterpret_cast<const f32x4*>(L + n);
    const f32x4* __restrict__ Pr4 = reinterpret_cast<const f32x4*>(P);
    const f32x4* __restrict__ Pi4 = reinterpret_cast<const f32x4*>(P + n);

    f32x2 sr = {0.f, 0.f}, si = {0.f, 0.f}, sint = {0.f, 0.f}, sph = {0.f, 0.f};
    int4 bounds = make_int4(COARSE_SENT, -1, COARSE_SENT, -1);

    const int nvec = n / 4;                  // 8192 float4s per half-row
    const int nit  = nvec / nt;              // 16 for the target shape

    if (nit * nt == nvec) {
        const int wave = tid >> 6;
        int slot0 = (2 * wave) % nit;        // waves spread across phases
        for (int j = 0; j < nit; ++j) {
            int slot = slot0 + j;
            slot = (slot >= nit) ? slot - nit : slot;
            const int v = tid + slot * nt;
            f32x4 a = Lr4[v], b = Li4[v], c = Pr4[v], d = Pi4[v];
            process_quad(a, b, c, d, v, sr, si, sint, sph, bounds);
        }
    } else {
        for (int v = tid; v < nvec; v += nt) {
            f32x4 a = Lr4[v], b = Li4[v], c = Pr4[v], d = Pi4[v];
            process_quad(a, b, c, d, v, sr, si, sint, sph, bounds);
        }
    }

    float4 sums = make_float4(sr.x + sr.y, si.x + si.y, sint.x + sint.y, sph.x + sph.y);
    float4 tot = blockReduceSum4(sums, s_f4);
    int4 b4 = blockReduceBounds(bounds, s_i4);

    // refine coarse (float4-granularity) bounds to exact element bounds
    if (tid < 4) s_b[tid] = (tid & 1) ? -1 : n;
    __syncthreads();
    if (tid < 16) {
        int which = tid >> 2;                     // 0:fr 1:lr 2:fi 3:li
        int k = tid & 3;
        const float* base = (which >= 2) ? (L + n) : L;
        int v4 = (which == 0) ? b4.x : (which == 1) ? b4.y : (which == 2) ? b4.z : b4.w;
        bool valid = (which & 1) ? (v4 >= 0) : (v4 < COARSE_SENT);
        if (valid) {
            int idx = v4 * 4 + k;
            if (fabsf(base[idx]) > SIG_THRESHOLD) {
                if (which & 1) atomicMax(&s_b[which], idx);
                else           atomicMin(&s_b[which], idx);
            }
        }
    }
    __syncthreads();
    int fr = s_b[0], lr = s_b[1], fi = s_b[2], li = s_b[3];
    if (fr == n) { fr = 0; lr = n - 1; }   // no significant element: scale 1 everywhere
    if (fi == n) { fi = 0; li = n - 1; }

    // extra 1x contribution for the two outside spans (usually ~empty)
    float4 osum = make_float4(0.f, 0.f, 0.f, 0.f);   // x: o_r, y: o_i
    for (int i = tid; i < fr; i += nt)          { float d = P[i] - L[i];         osum.x = fmaf(d, d, osum.x); }
    for (int i = lr + 1 + tid; i < n; i += nt)  { float d = P[i] - L[i];         osum.x = fmaf(d, d, osum.x); }
    for (int i = tid; i < fi; i += nt)          { float d = P[n + i] - L[n + i]; osum.y = fmaf(d, d, osum.y); }
    for (int i = li + 1 + tid; i < n; i += nt)  { float d = P[n + i] - L[n + i]; osum.y = fmaf(d, d, osum.y); }

    float4 otot = blockReduceSum4(osum, s_f4);

    if (tid == 0) {
        float wr = tot.x + otot.x;
        float wi = tot.y + otot.y;
        row_out[row] = (wr + wi + 10.0f * tot.z + 5.0f * tot.w) / (float)n;
    }
}

// ---------------- finalize: mean over rows ----------------
__global__ void __launch_bounds__(1024)
prl_finalize_kernel(const float* __restrict__ rows, float* __restrict__ out, int B) {
    __shared__ float4 s_f4[16];
    float4 v = make_float4(0.f, 0.f, 0.f, 0.f);
    for (int i = threadIdx.x; i < B; i += blockDim.x) v.x += rows[i];
    __syncthreads();
    v = waveReduceSum4(v);
    int lane = threadIdx.x & 63, wave = threadIdx.x >> 6;
    if (lane == 0) s_f4[wave] = v;
    __syncthreads();
    int nw = blockDim.x >> 6;
    float4 r = (threadIdx.x < nw) ? s_f4[threadIdx.x] : make_float4(0.f, 0.f, 0.f, 0.f);
    if (threadIdx.x < 64) r = waveReduceSum4(r);
    if (threadIdx.x == 0) out[0] = r.x / (float)B;
}

extern "C" void kernel_launch(void* const* d_in, const int* in_sizes, int n_in,
                              void* d_out, int out_size, void* d_ws, size_t ws_size,
                              hipStream_t stream) {
    const float* pred  = (const float*)d_in[0];
    const float* label = (const float*)d_in[1];
    // spectrogram (d_in[2]) is unused by the reference.

    const int B     = in_sizes[2] / (128 * 128);   // 1024
    const int two_n = in_sizes[0] / B;             // 65536
    const int n     = two_n / 2;                   // 32768

    float* row_out = (float*)d_ws;                 // B floats of scratch
    float* out     = (float*)d_out;

    prl_row_kernel<<<B, 512, 0, stream>>>(pred, label, row_out, n, two_n);
    prl_finalize_kernel<<<1, 1024, 0, stream>>>(row_out, out, B);
}